// Round 1
// baseline (1011.132 us; speedup 1.0000x reference)
//
#include <hip/hip_runtime.h>
#include <math.h>

#define M_TOK 8192
#define D_DIM 2048
#define G_GENES 4096
#define GD_DIM 256
#define KSEL 32
#define NCAND 40

typedef float f32x4 __attribute__((ext_vector_type(4)));
typedef short bf16x8 __attribute__((ext_vector_type(8)));

__device__ __forceinline__ void async_copy16(const void* g, void* lds) {
  __builtin_amdgcn_global_load_lds((const __attribute__((address_space(1))) void*)g,
                                   (__attribute__((address_space(3))) void*)lds, 16, 0, 0);
}

__device__ __forceinline__ unsigned short f2bf(float f) {
  unsigned int u = __float_as_uint(f);
  unsigned int r = (u + 0x7fffu + ((u >> 16) & 1u)) >> 16;
  return (unsigned short)r;
}

// ---------------- K1: RMSNorm -> r[t], xn_bf16 ----------------
__global__ __launch_bounds__(256) void k1_rmsnorm(const float* __restrict__ x,
                                                  const float* __restrict__ nw,
                                                  float* __restrict__ r_out,
                                                  unsigned short* __restrict__ xn_bf) {
  int t = blockIdx.x, tid = threadIdx.x;
  const float4* xr = (const float4*)(x + (size_t)t * D_DIM);
  float4 a = xr[tid], b = xr[tid + 256];
  double ss = (double)a.x*a.x + (double)a.y*a.y + (double)a.z*a.z + (double)a.w*a.w
            + (double)b.x*b.x + (double)b.y*b.y + (double)b.z*b.z + (double)b.w*b.w;
  for (int off = 32; off; off >>= 1) ss += __shfl_down(ss, off);
  __shared__ double sred[4];
  __shared__ float rshare;
  int lane = tid & 63, wv = tid >> 6;
  if (lane == 0) sred[wv] = ss;
  __syncthreads();
  if (tid == 0) {
    double tot = sred[0] + sred[1] + sred[2] + sred[3];
    float r = (float)(1.0 / sqrt(tot / (double)D_DIM + 1.1920928955078125e-7));
    rshare = r; r_out[t] = r;
  }
  __syncthreads();
  float r = rshare;
  const float4* nw4 = (const float4*)nw;
  float4 na = nw4[tid], nb = nw4[tid + 256];
  ushort4 oa, ob;
  oa.x = f2bf(a.x * r * na.x); oa.y = f2bf(a.y * r * na.y);
  oa.z = f2bf(a.z * r * na.z); oa.w = f2bf(a.w * r * na.w);
  ob.x = f2bf(b.x * r * nb.x); ob.y = f2bf(b.y * r * nb.y);
  ob.z = f2bf(b.z * r * nb.z); ob.w = f2bf(b.w * r * nb.w);
  ushort4* o4 = (ushort4*)(xn_bf + (size_t)t * D_DIM);
  o4[tid] = oa; o4[tid + 256] = ob;
}

// ---------------- K2: Wc fp32 -> bf16 ----------------
__global__ __launch_bounds__(256) void k2_cvt(const float* __restrict__ w,
                                              unsigned short* __restrict__ wb) {
  size_t i = (size_t)blockIdx.x * 256 + threadIdx.x;   // handles 8 elements
  const float4* w4 = (const float4*)w;
  float4 a = w4[2*i], b = w4[2*i+1];
  ushort4 oa, ob;
  oa.x = f2bf(a.x); oa.y = f2bf(a.y); oa.z = f2bf(a.z); oa.w = f2bf(a.w);
  ob.x = f2bf(b.x); ob.y = f2bf(b.y); ob.z = f2bf(b.z); ob.w = f2bf(b.w);
  ((ushort4*)wb)[2*i] = oa; ((ushort4*)wb)[2*i+1] = ob;
}

// ---------------- K3: approx logits GEMM (bf16 MFMA, 128x128 tile) ----------------
// A: xn_bf [M][K], B: Wc_bf [N][K] (both K-contiguous), C: bf16 logits [M][N]
__global__ __launch_bounds__(256) void k3_gemm_logits(const unsigned short* __restrict__ A,
                                                      const unsigned short* __restrict__ B,
                                                      unsigned short* __restrict__ C) {
  __shared__ unsigned short As[128 * 32];
  __shared__ unsigned short Bs[128 * 32];
  int tid = threadIdx.x;
  int lane = tid & 63, wv = tid >> 6;
  int bn = blockIdx.x, bm = blockIdx.y;
  int wr = wv >> 1, wc = wv & 1;
  f32x4 acc[4][4];
#pragma unroll
  for (int m = 0; m < 4; ++m)
#pragma unroll
    for (int n = 0; n < 4; ++n) acc[m][n] = (f32x4){0.f, 0.f, 0.f, 0.f};

  const int lrow = lane >> 2;        // row within 16-row chunk
  const int lcol = (lane & 3) * 8;   // element col within 32
  size_t abase = (size_t)(bm * 128) * D_DIM;
  size_t bbase = (size_t)(bn * 128) * D_DIM;

  for (int kt = 0; kt < D_DIM; kt += 32) {
    __syncthreads();
#pragma unroll
    for (int c = 0; c < 2; ++c) {
      int rr = (wv * 2 + c) * 16 + lrow;
      async_copy16(A + abase + (size_t)rr * D_DIM + kt + lcol, &As[(wv * 2 + c) * 512]);
      async_copy16(B + bbase + (size_t)rr * D_DIM + kt + lcol, &Bs[(wv * 2 + c) * 512]);
    }
    __syncthreads();
    bf16x8 fa[4], fb[4];
#pragma unroll
    for (int m = 0; m < 4; ++m)
      fa[m] = *(const bf16x8*)&As[(wr * 64 + m * 16 + (lane & 15)) * 32 + (lane >> 4) * 8];
#pragma unroll
    for (int n = 0; n < 4; ++n)
      fb[n] = *(const bf16x8*)&Bs[(wc * 64 + n * 16 + (lane & 15)) * 32 + (lane >> 4) * 8];
#pragma unroll
    for (int m = 0; m < 4; ++m)
#pragma unroll
      for (int n = 0; n < 4; ++n)
        acc[m][n] = __builtin_amdgcn_mfma_f32_16x16x32_bf16(fa[m], fb[n], acc[m][n], 0, 0, 0);
  }
#pragma unroll
  for (int m = 0; m < 4; ++m)
#pragma unroll
    for (int n = 0; n < 4; ++n)
#pragma unroll
      for (int j = 0; j < 4; ++j) {
        int row = bm * 128 + wr * 64 + m * 16 + (lane >> 4) * 4 + j;
        int col = bn * 128 + wc * 64 + n * 16 + (lane & 15);
        C[(size_t)row * G_GENES + col] = f2bf(acc[m][n][j]);
      }
}

// ---------------- K4: per-token top-40 candidates (1 wave / token) ----------------
__global__ __launch_bounds__(256) void k4_topk(const unsigned short* __restrict__ L,
                                               int* __restrict__ cand) {
  int wv = threadIdx.x >> 6, lane = threadIdx.x & 63;
  int t = blockIdx.x * 4 + wv;
  const unsigned short* lp = L + (size_t)t * G_GENES;
  float v[64];
#pragma unroll
  for (int i = 0; i < 8; ++i) {
    uint4 raw = *(const uint4*)(lp + i * 512 + lane * 8);
    v[i*8+0] = __uint_as_float(raw.x << 16);
    v[i*8+1] = __uint_as_float(raw.x & 0xffff0000u);
    v[i*8+2] = __uint_as_float(raw.y << 16);
    v[i*8+3] = __uint_as_float(raw.y & 0xffff0000u);
    v[i*8+4] = __uint_as_float(raw.z << 16);
    v[i*8+5] = __uint_as_float(raw.z & 0xffff0000u);
    v[i*8+6] = __uint_as_float(raw.w << 16);
    v[i*8+7] = __uint_as_float(raw.w & 0xffff0000u);
  }
  unsigned long long alive = ~0ull;
  for (int it = 0; it < NCAND; ++it) {
    float best = -3.0e38f; int bslot = 0;
#pragma unroll
    for (int s = 0; s < 64; ++s) {
      bool ok = (alive >> s) & 1ull;
      if (ok && v[s] > best) { best = v[s]; bslot = s; }
    }
    unsigned int g = ((unsigned)(bslot >> 3)) * 512u + (unsigned)lane * 8u + (unsigned)(bslot & 7);
    float m = best; unsigned int mg = g;
#pragma unroll
    for (int off = 32; off; off >>= 1) {
      float om = __shfl_xor(m, off);
      unsigned int og = __shfl_xor(mg, off);
      if (om > m || (om == m && og < mg)) { m = om; mg = og; }
    }
    if (lane == (int)((mg >> 3) & 63u)) {
      int s = (int)(((mg >> 9) << 3) | (mg & 7u));
      alive &= ~(1ull << s);
    }
    if (lane == 0) cand[(size_t)t * NCAND + it] = (int)mg;
  }
}

// ---------------- K5: exact fp64 rescore of candidates ----------------
__global__ __launch_bounds__(256) void k5_rescore(const float* __restrict__ x,
                                                  const float* __restrict__ r,
                                                  const float* __restrict__ nw,
                                                  const float* __restrict__ Wc,
                                                  const float* __restrict__ temp,
                                                  const int* __restrict__ cand,
                                                  double* __restrict__ cval) {
  int t = blockIdx.x;
  int wv = threadIdx.x >> 6, lane = threadIdx.x & 63;
  float rr = r[t];
  float tclamp = fmaxf(temp[0], 0.1f);
  float xl[32];
#pragma unroll
  for (int i = 0; i < 32; ++i)
    xl[i] = x[(size_t)t * D_DIM + i * 64 + lane] * rr * nw[i * 64 + lane];
#pragma unroll 1
  for (int j = 0; j < 10; ++j) {
    int g = cand[(size_t)t * NCAND + wv * 10 + j];
    const float* wrow = Wc + (size_t)g * D_DIM;
    double a0 = 0, a1 = 0, a2 = 0, a3 = 0;
#pragma unroll
    for (int i = 0; i < 32; i += 4) {
      a0 += (double)xl[i]     * (double)wrow[i * 64 + lane];
      a1 += (double)xl[i + 1] * (double)wrow[(i + 1) * 64 + lane];
      a2 += (double)xl[i + 2] * (double)wrow[(i + 2) * 64 + lane];
      a3 += (double)xl[i + 3] * (double)wrow[(i + 3) * 64 + lane];
    }
    double acc = (a0 + a1) + (a2 + a3);
#pragma unroll
    for (int off = 32; off; off >>= 1) acc += __shfl_down(acc, off);
    if (lane == 0) cval[(size_t)t * NCAND + wv * 10 + j] = acc / (double)tclamp;
  }
}

// ---------------- K6: select top-32, softmax, combine genes -> expressed ----------------
__global__ __launch_bounds__(256) void k6_express(const double* __restrict__ cval,
                                                  const int* __restrict__ cand,
                                                  const float* __restrict__ genes,
                                                  float* __restrict__ expr) {
  int t = blockIdx.x, tid = threadIdx.x;
  __shared__ double sval[NCAND];
  __shared__ int sidx[NCAND];
  __shared__ float sw[NCAND];
  if (tid < NCAND) {
    sval[tid] = cval[(size_t)t * NCAND + tid];
    sidx[tid] = cand[(size_t)t * NCAND + tid];
  }
  __syncthreads();
  if (tid < 64) {
    double v = (tid < NCAND) ? sval[tid] : -1.0e300;
    int gi = (tid < NCAND) ? sidx[tid] : 0x7fffffff;
    int rank = 0;
    for (int j = 0; j < NCAND; ++j) {
      double vj = sval[j]; int gj = sidx[j];
      if (vj > v || (vj == v && gj < gi)) rank++;
    }
    bool sel = (tid < NCAND) && (rank < KSEL);
    double vs = sel ? v : -1.0e300;
    double mx = vs;
    for (int off = 32; off; off >>= 1) { double o = __shfl_xor(mx, off); mx = fmax(mx, o); }
    double e = sel ? exp(v - mx) : 0.0;
    double ssum = e;
    for (int off = 32; off; off >>= 1) ssum += __shfl_xor(ssum, off);
    if (tid < NCAND) sw[tid] = (float)(e / ssum);
  }
  __syncthreads();
  float acc = 0.f;
#pragma unroll 1
  for (int k = 0; k < NCAND; ++k)
    acc += sw[k] * genes[(size_t)sidx[k] * GD_DIM + tid];
  expr[(size_t)t * GD_DIM + tid] = acc;
}

// ---------------- K7: fused down/up GEMM + tanh + xn + scale -> out ----------------
__global__ __launch_bounds__(256) void k7_out(const float* __restrict__ expr,
                                              const float* __restrict__ Wd,
                                              const float* __restrict__ Wu,
                                              const float* __restrict__ x,
                                              const float* __restrict__ r,
                                              const float* __restrict__ nw,
                                              const float* __restrict__ scale_p,
                                              float* __restrict__ out) {
  __shared__ float Et[64][68];  // [k][token]
  __shared__ float Dt[64][68];  // [k][d]
  __shared__ float Ut[64][68];
  int tid = threadIdx.x;
  int tx = tid & 15, ty = tid >> 4;
  int bt = blockIdx.y * 64, bd = blockIdx.x * 64;
  float accD[4][4], accU[4][4];
#pragma unroll
  for (int i = 0; i < 4; ++i)
#pragma unroll
    for (int j = 0; j < 4; ++j) { accD[i][j] = 0.f; accU[i][j] = 0.f; }

  for (int kc = 0; kc < GD_DIM; kc += 64) {
    __syncthreads();
#pragma unroll
    for (int q = 0; q < 4; ++q) {
      int off = q * 1024 + tid * 4;
      int row = off >> 6;
      int col = off & 63;
      float4 e = *(const float4*)&expr[(size_t)(bt + row) * GD_DIM + kc + col];
      Et[col][row] = e.x; Et[col+1][row] = e.y; Et[col+2][row] = e.z; Et[col+3][row] = e.w;
      float4 d = *(const float4*)&Wd[(size_t)(bd + row) * GD_DIM + kc + col];
      Dt[col][row] = d.x; Dt[col+1][row] = d.y; Dt[col+2][row] = d.z; Dt[col+3][row] = d.w;
      float4 u = *(const float4*)&Wu[(size_t)(bd + row) * GD_DIM + kc + col];
      Ut[col][row] = u.x; Ut[col+1][row] = u.y; Ut[col+2][row] = u.z; Ut[col+3][row] = u.w;
    }
    __syncthreads();
#pragma unroll
    for (int k = 0; k < 64; ++k) {
      f32x4 a  = *(const f32x4*)&Et[k][ty * 4];
      f32x4 bD = *(const f32x4*)&Dt[k][tx * 4];
      f32x4 bU = *(const f32x4*)&Ut[k][tx * 4];
#pragma unroll
      for (int i = 0; i < 4; ++i)
#pragma unroll
        for (int j = 0; j < 4; ++j) {
          accD[i][j] += a[i] * bD[j];
          accU[i][j] += a[i] * bU[j];
        }
    }
  }
  float sc = scale_p[0];
#pragma unroll
  for (int i = 0; i < 4; ++i) {
    int token = bt + ty * 4 + i;
    float rr = r[token];
    float4 xv = *(const float4*)&x[(size_t)token * D_DIM + bd + tx * 4];
    float4 nv = *(const float4*)&nw[bd + tx * 4];
    float4 o;
    o.x = tanhf(accD[i][0]) * (xv.x * rr * nv.x) * accU[i][0] * sc;
    o.y = tanhf(accD[i][1]) * (xv.y * rr * nv.y) * accU[i][1] * sc;
    o.z = tanhf(accD[i][2]) * (xv.z * rr * nv.z) * accU[i][2] * sc;
    o.w = tanhf(accD[i][3]) * (xv.w * rr * nv.w) * accU[i][3] * sc;
    *(float4*)&out[(size_t)token * D_DIM + bd + tx * 4] = o;
  }
}

extern "C" void kernel_launch(void* const* d_in, const int* in_sizes, int n_in,
                              void* d_out, int out_size, void* d_ws, size_t ws_size,
                              hipStream_t stream) {
  const float* x       = (const float*)d_in[0];
  const float* Wc      = (const float*)d_in[1];
  const float* temp    = (const float*)d_in[2];
  const float* genes   = (const float*)d_in[3];
  const float* Wd      = (const float*)d_in[4];
  const float* Wu      = (const float*)d_in[5];
  const float* nw      = (const float*)d_in[6];
  const float* scale_p = (const float*)d_in[7];

  char* ws = (char*)d_ws;
  float* r_buf          = (float*)ws;                                   // 32 KB
  unsigned short* xn_bf = (unsigned short*)(ws + 65536);                // 32 MB
  unsigned short* wc_bf = (unsigned short*)(ws + 65536 + (size_t)M_TOK * D_DIM * 2);   // 16 MB
  char* p = ws + 65536 + (size_t)M_TOK * D_DIM * 2 + (size_t)G_GENES * D_DIM * 2;
  int* cand    = (int*)p;                       p += (size_t)M_TOK * NCAND * 4;
  double* cval = (double*)p;                    p += (size_t)M_TOK * NCAND * 8;
  float* expr  = (float*)p;

  unsigned short* logits_bf = (unsigned short*)d_out;  // 33.5M bf16 == 64 MB == d_out

  k1_rmsnorm<<<dim3(M_TOK), dim3(256), 0, stream>>>(x, nw, r_buf, xn_bf);
  k2_cvt<<<dim3((G_GENES * D_DIM) / (256 * 8)), dim3(256), 0, stream>>>(Wc, wc_bf);
  k3_gemm_logits<<<dim3(G_GENES / 128, M_TOK / 128), dim3(256), 0, stream>>>(xn_bf, wc_bf, logits_bf);
  k4_topk<<<dim3(M_TOK / 4), dim3(256), 0, stream>>>(logits_bf, cand);
  k5_rescore<<<dim3(M_TOK), dim3(256), 0, stream>>>(x, r_buf, nw, Wc, temp, cand, cval);
  k6_express<<<dim3(M_TOK), dim3(256), 0, stream>>>(cval, cand, genes, expr);
  k7_out<<<dim3(D_DIM / 64, M_TOK / 64), dim3(256), 0, stream>>>(expr, Wd, Wu, x, r_buf, nw, scale_p, (float*)d_out);
}

// Round 2
// 937.218 us; speedup vs baseline: 1.0789x; 1.0789x over previous
//
#include <hip/hip_runtime.h>
#include <math.h>

#define M_TOK 8192
#define D_DIM 2048
#define G_GENES 4096
#define GD_DIM 256
#define KSEL 32
#define NCAND 40

typedef float f32x4 __attribute__((ext_vector_type(4)));
typedef short bf16x8 __attribute__((ext_vector_type(8)));

__device__ __forceinline__ void async_copy16(const void* g, void* lds) {
  __builtin_amdgcn_global_load_lds((const __attribute__((address_space(1))) void*)g,
                                   (__attribute__((address_space(3))) void*)lds, 16, 0, 0);
}

__device__ __forceinline__ unsigned short f2bf(float f) {
  unsigned int u = __float_as_uint(f);
  unsigned int r = (u + 0x7fffu + ((u >> 16) & 1u)) >> 16;
  return (unsigned short)r;
}
__device__ __forceinline__ float bf2f(unsigned short h) {
  return __uint_as_float(((unsigned int)h) << 16);
}

// ---------------- K1: RMSNorm -> r[t], xn_bf16 ----------------
__global__ __launch_bounds__(256) void k1_rmsnorm(const float* __restrict__ x,
                                                  const float* __restrict__ nw,
                                                  float* __restrict__ r_out,
                                                  unsigned short* __restrict__ xn_bf) {
  int t = blockIdx.x, tid = threadIdx.x;
  const float4* xr = (const float4*)(x + (size_t)t * D_DIM);
  float4 a = xr[tid], b = xr[tid + 256];
  double ss = (double)a.x*a.x + (double)a.y*a.y + (double)a.z*a.z + (double)a.w*a.w
            + (double)b.x*b.x + (double)b.y*b.y + (double)b.z*b.z + (double)b.w*b.w;
  for (int off = 32; off; off >>= 1) ss += __shfl_down(ss, off);
  __shared__ double sred[4];
  __shared__ float rshare;
  int lane = tid & 63, wv = tid >> 6;
  if (lane == 0) sred[wv] = ss;
  __syncthreads();
  if (tid == 0) {
    double tot = sred[0] + sred[1] + sred[2] + sred[3];
    float r = (float)(1.0 / sqrt(tot / (double)D_DIM + 1.1920928955078125e-7));
    rshare = r; r_out[t] = r;
  }
  __syncthreads();
  float r = rshare;
  const float4* nw4 = (const float4*)nw;
  float4 na = nw4[tid], nb = nw4[tid + 256];
  ushort4 oa, ob;
  oa.x = f2bf(a.x * r * na.x); oa.y = f2bf(a.y * r * na.y);
  oa.z = f2bf(a.z * r * na.z); oa.w = f2bf(a.w * r * na.w);
  ob.x = f2bf(b.x * r * nb.x); ob.y = f2bf(b.y * r * nb.y);
  ob.z = f2bf(b.z * r * nb.z); ob.w = f2bf(b.w * r * nb.w);
  ushort4* o4 = (ushort4*)(xn_bf + (size_t)t * D_DIM);
  o4[tid] = oa; o4[tid + 256] = ob;
}

// ---------------- K2: Wc fp32 -> bf16 ----------------
__global__ __launch_bounds__(256) void k2_cvt(const float* __restrict__ w,
                                              unsigned short* __restrict__ wb) {
  size_t i = (size_t)blockIdx.x * 256 + threadIdx.x;   // handles 8 elements
  const float4* w4 = (const float4*)w;
  float4 a = w4[2*i], b = w4[2*i+1];
  ushort4 oa, ob;
  oa.x = f2bf(a.x); oa.y = f2bf(a.y); oa.z = f2bf(a.z); oa.w = f2bf(a.w);
  ob.x = f2bf(b.x); ob.y = f2bf(b.y); ob.z = f2bf(b.z); ob.w = f2bf(b.w);
  ((ushort4*)wb)[2*i] = oa; ((ushort4*)wb)[2*i+1] = ob;
}

// ---------------- K2b: split Wd/Wu into bf16 hi+lo ----------------
__global__ __launch_bounds__(256) void k2b_split(const float* __restrict__ wd,
                                                 const float* __restrict__ wu,
                                                 unsigned short* __restrict__ wdh,
                                                 unsigned short* __restrict__ wdl,
                                                 unsigned short* __restrict__ wuh,
                                                 unsigned short* __restrict__ wul) {
  const float* src = blockIdx.y ? wu : wd;
  unsigned short* dh = blockIdx.y ? wuh : wdh;
  unsigned short* dl = blockIdx.y ? wul : wdl;
  size_t i = (size_t)blockIdx.x * 256 + threadIdx.x;   // float4 index
  float4 v = ((const float4*)src)[i];
  ushort4 h, l;
  h.x = f2bf(v.x); l.x = f2bf(v.x - bf2f(h.x));
  h.y = f2bf(v.y); l.y = f2bf(v.y - bf2f(h.y));
  h.z = f2bf(v.z); l.z = f2bf(v.z - bf2f(h.z));
  h.w = f2bf(v.w); l.w = f2bf(v.w - bf2f(h.w));
  ((ushort4*)dh)[i] = h;
  ((ushort4*)dl)[i] = l;
}

// ---------------- K3: approx logits GEMM (bf16 MFMA, 128x128 tile) ----------------
__global__ __launch_bounds__(256) void k3_gemm_logits(const unsigned short* __restrict__ A,
                                                      const unsigned short* __restrict__ B,
                                                      unsigned short* __restrict__ C) {
  __shared__ unsigned short As[128 * 32];
  __shared__ unsigned short Bs[128 * 32];
  int tid = threadIdx.x;
  int lane = tid & 63, wv = tid >> 6;
  // bijective XCD swizzle over 2048 blocks (2048 % 8 == 0)
  int lin = blockIdx.y * gridDim.x + blockIdx.x;
  int swz = (lin & 7) * (2048 / 8) + (lin >> 3);
  int bn = swz & 31, bm = swz >> 5;
  int wr = wv >> 1, wc = wv & 1;
  f32x4 acc[4][4];
#pragma unroll
  for (int m = 0; m < 4; ++m)
#pragma unroll
    for (int n = 0; n < 4; ++n) acc[m][n] = (f32x4){0.f, 0.f, 0.f, 0.f};

  const int lrow = lane >> 2;
  const int lcol = (lane & 3) * 8;
  size_t abase = (size_t)(bm * 128) * D_DIM;
  size_t bbase = (size_t)(bn * 128) * D_DIM;

  for (int kt = 0; kt < D_DIM; kt += 32) {
    __syncthreads();
#pragma unroll
    for (int c = 0; c < 2; ++c) {
      int rr = (wv * 2 + c) * 16 + lrow;
      async_copy16(A + abase + (size_t)rr * D_DIM + kt + lcol, &As[(wv * 2 + c) * 512]);
      async_copy16(B + bbase + (size_t)rr * D_DIM + kt + lcol, &Bs[(wv * 2 + c) * 512]);
    }
    __syncthreads();
    bf16x8 fa[4], fb[4];
#pragma unroll
    for (int m = 0; m < 4; ++m)
      fa[m] = *(const bf16x8*)&As[(wr * 64 + m * 16 + (lane & 15)) * 32 + (lane >> 4) * 8];
#pragma unroll
    for (int n = 0; n < 4; ++n)
      fb[n] = *(const bf16x8*)&Bs[(wc * 64 + n * 16 + (lane & 15)) * 32 + (lane >> 4) * 8];
#pragma unroll
    for (int m = 0; m < 4; ++m)
#pragma unroll
      for (int n = 0; n < 4; ++n)
        acc[m][n] = __builtin_amdgcn_mfma_f32_16x16x32_bf16(fa[m], fb[n], acc[m][n], 0, 0, 0);
  }
#pragma unroll
  for (int m = 0; m < 4; ++m)
#pragma unroll
    for (int n = 0; n < 4; ++n)
#pragma unroll
      for (int j = 0; j < 4; ++j) {
        int row = bm * 128 + wr * 64 + m * 16 + (lane >> 4) * 4 + j;
        int col = bn * 128 + wc * 64 + n * 16 + (lane & 15);
        C[(size_t)row * G_GENES + col] = f2bf(acc[m][n][j]);
      }
}

// ---------------- K4: per-token top-40 candidates (1 wave / token) ----------------
__global__ __launch_bounds__(256) void k4_topk(const unsigned short* __restrict__ L,
                                               int* __restrict__ cand) {
  int wv = threadIdx.x >> 6, lane = threadIdx.x & 63;
  int t = blockIdx.x * 4 + wv;
  const unsigned short* lp = L + (size_t)t * G_GENES;
  float v[64];
#pragma unroll
  for (int i = 0; i < 8; ++i) {
    uint4 raw = *(const uint4*)(lp + i * 512 + lane * 8);
    v[i*8+0] = __uint_as_float(raw.x << 16);
    v[i*8+1] = __uint_as_float(raw.x & 0xffff0000u);
    v[i*8+2] = __uint_as_float(raw.y << 16);
    v[i*8+3] = __uint_as_float(raw.y & 0xffff0000u);
    v[i*8+4] = __uint_as_float(raw.z << 16);
    v[i*8+5] = __uint_as_float(raw.z & 0xffff0000u);
    v[i*8+6] = __uint_as_float(raw.w << 16);
    v[i*8+7] = __uint_as_float(raw.w & 0xffff0000u);
  }
  unsigned long long alive = ~0ull;
  for (int it = 0; it < NCAND; ++it) {
    float best = -3.0e38f; int bslot = 0;
#pragma unroll
    for (int s = 0; s < 64; ++s) {
      bool ok = (alive >> s) & 1ull;
      if (ok && v[s] > best) { best = v[s]; bslot = s; }
    }
    unsigned int g = ((unsigned)(bslot >> 3)) * 512u + (unsigned)lane * 8u + (unsigned)(bslot & 7);
    float m = best; unsigned int mg = g;
#pragma unroll
    for (int off = 32; off; off >>= 1) {
      float om = __shfl_xor(m, off);
      unsigned int og = __shfl_xor(mg, off);
      if (om > m || (om == m && og < mg)) { m = om; mg = og; }
    }
    if (lane == (int)((mg >> 3) & 63u)) {
      int s = (int)(((mg >> 9) << 3) | (mg & 7u));
      alive &= ~(1ull << s);
    }
    if (lane == 0) cand[(size_t)t * NCAND + it] = (int)mg;
  }
}

// ---------------- K5: exact fp64 rescore (8 waves/token, dwordx4 gathers) ----------------
__global__ __launch_bounds__(512) void k5_rescore(const float* __restrict__ x,
                                                  const float* __restrict__ r,
                                                  const float* __restrict__ nw,
                                                  const float* __restrict__ Wc,
                                                  const float* __restrict__ temp,
                                                  const int* __restrict__ cand,
                                                  double* __restrict__ cval) {
  int t = blockIdx.x;
  int wv = threadIdx.x >> 6, lane = threadIdx.x & 63;
  float rr = r[t];
  float tclamp = fmaxf(temp[0], 0.1f);
  const float4* x4 = (const float4*)(x + (size_t)t * D_DIM);
  const float4* nw4 = (const float4*)nw;
  float4 xl[8];
#pragma unroll
  for (int i = 0; i < 8; ++i) {
    float4 xv = x4[i * 64 + lane];
    float4 nv = nw4[i * 64 + lane];
    xl[i].x = xv.x * rr * nv.x;
    xl[i].y = xv.y * rr * nv.y;
    xl[i].z = xv.z * rr * nv.z;
    xl[i].w = xv.w * rr * nv.w;
  }
#pragma unroll 1
  for (int j = 0; j < 5; ++j) {
    int g = cand[(size_t)t * NCAND + wv * 5 + j];
    const float4* w4 = (const float4*)(Wc + (size_t)g * D_DIM);
    double a0 = 0, a1 = 0, a2 = 0, a3 = 0;
#pragma unroll
    for (int i = 0; i < 8; ++i) {
      float4 wr4 = w4[i * 64 + lane];
      a0 += (double)xl[i].x * (double)wr4.x;
      a1 += (double)xl[i].y * (double)wr4.y;
      a2 += (double)xl[i].z * (double)wr4.z;
      a3 += (double)xl[i].w * (double)wr4.w;
    }
    double acc = (a0 + a1) + (a2 + a3);
#pragma unroll
    for (int off = 32; off; off >>= 1) acc += __shfl_down(acc, off);
    if (lane == 0) cval[(size_t)t * NCAND + wv * 5 + j] = acc / (double)tclamp;
  }
}

// ---------------- K6: select top-32, softmax, combine -> expressed (bf16 hi/lo) ----------------
__global__ __launch_bounds__(256) void k6_express(const double* __restrict__ cval,
                                                  const int* __restrict__ cand,
                                                  const float* __restrict__ genes,
                                                  unsigned short* __restrict__ e_hi,
                                                  unsigned short* __restrict__ e_lo) {
  int t = blockIdx.x, tid = threadIdx.x;
  __shared__ double sval[NCAND];
  __shared__ int sidx[NCAND];
  __shared__ float sw[NCAND];
  if (tid < NCAND) {
    sval[tid] = cval[(size_t)t * NCAND + tid];
    sidx[tid] = cand[(size_t)t * NCAND + tid];
  }
  __syncthreads();
  if (tid < 64) {
    double v = (tid < NCAND) ? sval[tid] : -1.0e300;
    int gi = (tid < NCAND) ? sidx[tid] : 0x7fffffff;
    int rank = 0;
    for (int j = 0; j < NCAND; ++j) {
      double vj = sval[j]; int gj = sidx[j];
      if (vj > v || (vj == v && gj < gi)) rank++;
    }
    bool sel = (tid < NCAND) && (rank < KSEL);
    double vs = sel ? v : -1.0e300;
    double mx = vs;
    for (int off = 32; off; off >>= 1) { double o = __shfl_xor(mx, off); mx = fmax(mx, o); }
    double e = sel ? exp(v - mx) : 0.0;
    double ssum = e;
    for (int off = 32; off; off >>= 1) ssum += __shfl_xor(ssum, off);
    if (tid < NCAND) sw[tid] = (float)(e / ssum);
  }
  __syncthreads();
  float acc = 0.f;
#pragma unroll 1
  for (int k = 0; k < NCAND; ++k)
    acc += sw[k] * genes[(size_t)sidx[k] * GD_DIM + tid];
  unsigned short h = f2bf(acc);
  unsigned short l = f2bf(acc - bf2f(h));
  e_hi[(size_t)t * GD_DIM + tid] = h;
  e_lo[(size_t)t * GD_DIM + tid] = l;
}

// ---------------- K7: bf16-split MFMA down/up GEMM + tanh + xn + scale -> out ----------------
// A = expressed [M][256] (hi/lo), B = Wd/Wu [2048][256] (hi/lo). Tile 128(M) x 64(N), BK=32.
__global__ __launch_bounds__(256) void k7_mfma(const unsigned short* __restrict__ e_hi,
                                               const unsigned short* __restrict__ e_lo,
                                               const unsigned short* __restrict__ wdh,
                                               const unsigned short* __restrict__ wdl,
                                               const unsigned short* __restrict__ wuh,
                                               const unsigned short* __restrict__ wul,
                                               const float* __restrict__ x,
                                               const float* __restrict__ r,
                                               const float* __restrict__ nw,
                                               const float* __restrict__ scale_p,
                                               float* __restrict__ out) {
  __shared__ unsigned short Ah[128 * 32], Al[128 * 32];
  __shared__ unsigned short Dh[64 * 32], Dl[64 * 32], Uh[64 * 32], Ul[64 * 32];
  int tid = threadIdx.x;
  int lane = tid & 63, wv = tid >> 6;
  int bn = blockIdx.x, bm = blockIdx.y;
  int wr = wv >> 1, wc = wv & 1;   // wave tile: 64(M) x 32(N)
  const int lrow = lane >> 2;
  const int lcol = (lane & 3) * 8;

  f32x4 accD[4][2], accU[4][2];
#pragma unroll
  for (int m = 0; m < 4; ++m)
#pragma unroll
    for (int n = 0; n < 2; ++n) {
      accD[m][n] = (f32x4){0.f, 0.f, 0.f, 0.f};
      accU[m][n] = (f32x4){0.f, 0.f, 0.f, 0.f};
    }

  for (int kt = 0; kt < GD_DIM; kt += 32) {
    __syncthreads();
#pragma unroll
    for (int c = 0; c < 8; ++c) {
      int cid = wv * 8 + c;
      if (cid < 8) {
        async_copy16(e_hi + (size_t)(bm * 128 + cid * 16 + lrow) * GD_DIM + kt + lcol,
                     &Ah[cid * 512]);
      } else if (cid < 16) {
        int cc = cid - 8;
        async_copy16(e_lo + (size_t)(bm * 128 + cc * 16 + lrow) * GD_DIM + kt + lcol,
                     &Al[cc * 512]);
      } else if (cid < 20) {
        int cc = cid - 16;
        async_copy16(wdh + (size_t)(bn * 64 + cc * 16 + lrow) * GD_DIM + kt + lcol,
                     &Dh[cc * 512]);
      } else if (cid < 24) {
        int cc = cid - 20;
        async_copy16(wdl + (size_t)(bn * 64 + cc * 16 + lrow) * GD_DIM + kt + lcol,
                     &Dl[cc * 512]);
      } else if (cid < 28) {
        int cc = cid - 24;
        async_copy16(wuh + (size_t)(bn * 64 + cc * 16 + lrow) * GD_DIM + kt + lcol,
                     &Uh[cc * 512]);
      } else {
        int cc = cid - 28;
        async_copy16(wul + (size_t)(bn * 64 + cc * 16 + lrow) * GD_DIM + kt + lcol,
                     &Ul[cc * 512]);
      }
    }
    __syncthreads();
    bf16x8 fah[4], fal[4], fdh[2], fdl[2], fuh[2], ful[2];
#pragma unroll
    for (int m = 0; m < 4; ++m) {
      int off = (wr * 64 + m * 16 + (lane & 15)) * 32 + (lane >> 4) * 8;
      fah[m] = *(const bf16x8*)&Ah[off];
      fal[m] = *(const bf16x8*)&Al[off];
    }
#pragma unroll
    for (int n = 0; n < 2; ++n) {
      int off = (wc * 32 + n * 16 + (lane & 15)) * 32 + (lane >> 4) * 8;
      fdh[n] = *(const bf16x8*)&Dh[off];
      fdl[n] = *(const bf16x8*)&Dl[off];
      fuh[n] = *(const bf16x8*)&Uh[off];
      ful[n] = *(const bf16x8*)&Ul[off];
    }
#pragma unroll
    for (int m = 0; m < 4; ++m)
#pragma unroll
      for (int n = 0; n < 2; ++n) {
        accD[m][n] = __builtin_amdgcn_mfma_f32_16x16x32_bf16(fah[m], fdh[n], accD[m][n], 0, 0, 0);
        accD[m][n] = __builtin_amdgcn_mfma_f32_16x16x32_bf16(fah[m], fdl[n], accD[m][n], 0, 0, 0);
        accD[m][n] = __builtin_amdgcn_mfma_f32_16x16x32_bf16(fal[m], fdh[n], accD[m][n], 0, 0, 0);
        accU[m][n] = __builtin_amdgcn_mfma_f32_16x16x32_bf16(fah[m], fuh[n], accU[m][n], 0, 0, 0);
        accU[m][n] = __builtin_amdgcn_mfma_f32_16x16x32_bf16(fah[m], ful[n], accU[m][n], 0, 0, 0);
        accU[m][n] = __builtin_amdgcn_mfma_f32_16x16x32_bf16(fal[m], fuh[n], accU[m][n], 0, 0, 0);
      }
  }
  float sc = scale_p[0];
#pragma unroll
  for (int m = 0; m < 4; ++m)
#pragma unroll
    for (int j = 0; j < 4; ++j) {
      int token = bm * 128 + wr * 64 + m * 16 + (lane >> 4) * 4 + j;
      float rr = r[token];
#pragma unroll
      for (int n = 0; n < 2; ++n) {
        int d = bn * 64 + wc * 32 + n * 16 + (lane & 15);
        float xn = x[(size_t)token * D_DIM + d] * rr * nw[d];
        out[(size_t)token * D_DIM + d] = tanhf(accD[m][n][j]) * xn * accU[m][n][j] * sc;
      }
    }
}

extern "C" void kernel_launch(void* const* d_in, const int* in_sizes, int n_in,
                              void* d_out, int out_size, void* d_ws, size_t ws_size,
                              hipStream_t stream) {
  const float* x       = (const float*)d_in[0];
  const float* Wc      = (const float*)d_in[1];
  const float* temp    = (const float*)d_in[2];
  const float* genes   = (const float*)d_in[3];
  const float* Wd      = (const float*)d_in[4];
  const float* Wu      = (const float*)d_in[5];
  const float* nw      = (const float*)d_in[6];
  const float* scale_p = (const float*)d_in[7];

  char* ws = (char*)d_ws;
  float* r_buf          = (float*)ws;                                   // 32 KB (64 KB reserved)
  unsigned short* xn_bf = (unsigned short*)(ws + 65536);                // 32 MB (free after k3)
  unsigned short* wc_bf = (unsigned short*)(ws + 65536 + (size_t)M_TOK * D_DIM * 2);   // 16 MB
  char* p = ws + 65536 + (size_t)M_TOK * D_DIM * 2 + (size_t)G_GENES * D_DIM * 2;
  int* cand    = (int*)p;                       p += (size_t)M_TOK * NCAND * 4;
  double* cval = (double*)p;                    p += (size_t)M_TOK * NCAND * 8;
  unsigned short* e_hi = (unsigned short*)p;    p += (size_t)M_TOK * GD_DIM * 2;
  unsigned short* e_lo = (unsigned short*)p;

  // Wd/Wu bf16 hi/lo splits live in the xn_bf region (dead after k3): 4 x 1 MB
  unsigned short* wdh = (unsigned short*)(ws + 65536);
  unsigned short* wdl = wdh + (size_t)D_DIM * GD_DIM;
  unsigned short* wuh = wdl + (size_t)D_DIM * GD_DIM;
  unsigned short* wul = wuh + (size_t)D_DIM * GD_DIM;

  unsigned short* logits_bf = (unsigned short*)d_out;  // 33.5M bf16 == 64 MB == d_out

  k1_rmsnorm<<<dim3(M_TOK), dim3(256), 0, stream>>>(x, nw, r_buf, xn_bf);
  k2_cvt<<<dim3((G_GENES * D_DIM) / (256 * 8)), dim3(256), 0, stream>>>(Wc, wc_bf);
  k3_gemm_logits<<<dim3(G_GENES / 128, M_TOK / 128), dim3(256), 0, stream>>>(xn_bf, wc_bf, logits_bf);
  k4_topk<<<dim3(M_TOK / 4), dim3(256), 0, stream>>>(logits_bf, cand);
  k2b_split<<<dim3((D_DIM * GD_DIM) / (256 * 4), 2), dim3(256), 0, stream>>>(Wd, Wu, wdh, wdl, wuh, wul);
  k5_rescore<<<dim3(M_TOK), dim3(512), 0, stream>>>(x, r_buf, nw, Wc, temp, cand, cval);
  k6_express<<<dim3(M_TOK), dim3(256), 0, stream>>>(cval, cand, genes, e_hi, e_lo);
  k7_mfma<<<dim3(D_DIM / 64, M_TOK / 128), dim3(256), 0, stream>>>(e_hi, e_lo, wdh, wdl, wuh, wul,
                                                                   x, r_buf, nw, scale_p, (float*)d_out);
}

// Round 3
// 901.260 us; speedup vs baseline: 1.1219x; 1.0399x over previous
//
#include <hip/hip_runtime.h>
#include <math.h>

#define M_TOK 8192
#define D_DIM 2048
#define G_GENES 4096
#define GD_DIM 256
#define KSEL 32
#define NCAND 40

typedef float f32x4 __attribute__((ext_vector_type(4)));
typedef short bf16x8 __attribute__((ext_vector_type(8)));

__device__ __forceinline__ void async_copy16(const void* g, void* lds) {
  __builtin_amdgcn_global_load_lds((const __attribute__((address_space(1))) void*)g,
                                   (__attribute__((address_space(3))) void*)lds, 16, 0, 0);
}

__device__ __forceinline__ unsigned short f2bf(float f) {
  unsigned int u = __float_as_uint(f);
  unsigned int r = (u + 0x7fffu + ((u >> 16) & 1u)) >> 16;
  return (unsigned short)r;
}
__device__ __forceinline__ float bf2f(unsigned short h) {
  return __uint_as_float(((unsigned int)h) << 16);
}

// ---------------- K1: RMSNorm -> r[t], xn_bf16 ----------------
__global__ __launch_bounds__(256) void k1_rmsnorm(const float* __restrict__ x,
                                                  const float* __restrict__ nw,
                                                  float* __restrict__ r_out,
                                                  unsigned short* __restrict__ xn_bf) {
  int t = blockIdx.x, tid = threadIdx.x;
  const float4* xr = (const float4*)(x + (size_t)t * D_DIM);
  float4 a = xr[tid], b = xr[tid + 256];
  double ss = (double)a.x*a.x + (double)a.y*a.y + (double)a.z*a.z + (double)a.w*a.w
            + (double)b.x*b.x + (double)b.y*b.y + (double)b.z*b.z + (double)b.w*b.w;
  for (int off = 32; off; off >>= 1) ss += __shfl_down(ss, off);
  __shared__ double sred[4];
  __shared__ float rshare;
  int lane = tid & 63, wv = tid >> 6;
  if (lane == 0) sred[wv] = ss;
  __syncthreads();
  if (tid == 0) {
    double tot = sred[0] + sred[1] + sred[2] + sred[3];
    float r = (float)(1.0 / sqrt(tot / (double)D_DIM + 1.1920928955078125e-7));
    rshare = r; r_out[t] = r;
  }
  __syncthreads();
  float r = rshare;
  const float4* nw4 = (const float4*)nw;
  float4 na = nw4[tid], nb = nw4[tid + 256];
  ushort4 oa, ob;
  oa.x = f2bf(a.x * r * na.x); oa.y = f2bf(a.y * r * na.y);
  oa.z = f2bf(a.z * r * na.z); oa.w = f2bf(a.w * r * na.w);
  ob.x = f2bf(b.x * r * nb.x); ob.y = f2bf(b.y * r * nb.y);
  ob.z = f2bf(b.z * r * nb.z); ob.w = f2bf(b.w * r * nb.w);
  ushort4* o4 = (ushort4*)(xn_bf + (size_t)t * D_DIM);
  o4[tid] = oa; o4[tid + 256] = ob;
}

// ---------------- K2: Wc fp32 -> bf16 ----------------
__global__ __launch_bounds__(256) void k2_cvt(const float* __restrict__ w,
                                              unsigned short* __restrict__ wb) {
  size_t i = (size_t)blockIdx.x * 256 + threadIdx.x;   // handles 8 elements
  const float4* w4 = (const float4*)w;
  float4 a = w4[2*i], b = w4[2*i+1];
  ushort4 oa, ob;
  oa.x = f2bf(a.x); oa.y = f2bf(a.y); oa.z = f2bf(a.z); oa.w = f2bf(a.w);
  ob.x = f2bf(b.x); ob.y = f2bf(b.y); ob.z = f2bf(b.z); ob.w = f2bf(b.w);
  ((ushort4*)wb)[2*i] = oa; ((ushort4*)wb)[2*i+1] = ob;
}

// ---------------- K2b: split Wd/Wu into bf16 hi+lo ----------------
__global__ __launch_bounds__(256) void k2b_split(const float* __restrict__ wd,
                                                 const float* __restrict__ wu,
                                                 unsigned short* __restrict__ wdh,
                                                 unsigned short* __restrict__ wdl,
                                                 unsigned short* __restrict__ wuh,
                                                 unsigned short* __restrict__ wul) {
  const float* src = blockIdx.y ? wu : wd;
  unsigned short* dh = blockIdx.y ? wuh : wdh;
  unsigned short* dl = blockIdx.y ? wul : wdl;
  size_t i = (size_t)blockIdx.x * 256 + threadIdx.x;   // float4 index
  float4 v = ((const float4*)src)[i];
  ushort4 h, l;
  h.x = f2bf(v.x); l.x = f2bf(v.x - bf2f(h.x));
  h.y = f2bf(v.y); l.y = f2bf(v.y - bf2f(h.y));
  h.z = f2bf(v.z); l.z = f2bf(v.z - bf2f(h.z));
  h.w = f2bf(v.w); l.w = f2bf(v.w - bf2f(h.w));
  ((ushort4*)dh)[i] = h;
  ((ushort4*)dl)[i] = l;
}

// ---------------- K3: approx logits GEMM (bf16 MFMA, 128x128 tile) ----------------
__global__ __launch_bounds__(256) void k3_gemm_logits(const unsigned short* __restrict__ A,
                                                      const unsigned short* __restrict__ B,
                                                      unsigned short* __restrict__ C) {
  __shared__ unsigned short As[128 * 32];
  __shared__ unsigned short Bs[128 * 32];
  int tid = threadIdx.x;
  int lane = tid & 63, wv = tid >> 6;
  // bijective XCD swizzle over 2048 blocks (2048 % 8 == 0)
  int lin = blockIdx.y * gridDim.x + blockIdx.x;
  int swz = (lin & 7) * (2048 / 8) + (lin >> 3);
  int bn = swz & 31, bm = swz >> 5;
  int wr = wv >> 1, wc = wv & 1;
  f32x4 acc[4][4];
#pragma unroll
  for (int m = 0; m < 4; ++m)
#pragma unroll
    for (int n = 0; n < 4; ++n) acc[m][n] = (f32x4){0.f, 0.f, 0.f, 0.f};

  const int lrow = lane >> 2;
  const int lcol = (lane & 3) * 8;
  size_t abase = (size_t)(bm * 128) * D_DIM;
  size_t bbase = (size_t)(bn * 128) * D_DIM;

  for (int kt = 0; kt < D_DIM; kt += 32) {
    __syncthreads();
#pragma unroll
    for (int c = 0; c < 2; ++c) {
      int rr = (wv * 2 + c) * 16 + lrow;
      async_copy16(A + abase + (size_t)rr * D_DIM + kt + lcol, &As[(wv * 2 + c) * 512]);
      async_copy16(B + bbase + (size_t)rr * D_DIM + kt + lcol, &Bs[(wv * 2 + c) * 512]);
    }
    __syncthreads();
    bf16x8 fa[4], fb[4];
#pragma unroll
    for (int m = 0; m < 4; ++m)
      fa[m] = *(const bf16x8*)&As[(wr * 64 + m * 16 + (lane & 15)) * 32 + (lane >> 4) * 8];
#pragma unroll
    for (int n = 0; n < 4; ++n)
      fb[n] = *(const bf16x8*)&Bs[(wc * 64 + n * 16 + (lane & 15)) * 32 + (lane >> 4) * 8];
#pragma unroll
    for (int m = 0; m < 4; ++m)
#pragma unroll
      for (int n = 0; n < 4; ++n)
        acc[m][n] = __builtin_amdgcn_mfma_f32_16x16x32_bf16(fa[m], fb[n], acc[m][n], 0, 0, 0);
  }
#pragma unroll
  for (int m = 0; m < 4; ++m)
#pragma unroll
    for (int n = 0; n < 4; ++n)
#pragma unroll
      for (int j = 0; j < 4; ++j) {
        int row = bm * 128 + wr * 64 + m * 16 + (lane >> 4) * 4 + j;
        int col = bn * 128 + wc * 64 + n * 16 + (lane & 15);
        C[(size_t)row * G_GENES + col] = f2bf(acc[m][n][j]);
      }
}

// ---------------- K4: per-token top-40 candidates (1 wave / token) ----------------
__global__ __launch_bounds__(256) void k4_topk(const unsigned short* __restrict__ L,
                                               int* __restrict__ cand) {
  int wv = threadIdx.x >> 6, lane = threadIdx.x & 63;
  int t = blockIdx.x * 4 + wv;
  const unsigned short* lp = L + (size_t)t * G_GENES;
  float v[64];
#pragma unroll
  for (int i = 0; i < 8; ++i) {
    uint4 raw = *(const uint4*)(lp + i * 512 + lane * 8);
    v[i*8+0] = __uint_as_float(raw.x << 16);
    v[i*8+1] = __uint_as_float(raw.x & 0xffff0000u);
    v[i*8+2] = __uint_as_float(raw.y << 16);
    v[i*8+3] = __uint_as_float(raw.y & 0xffff0000u);
    v[i*8+4] = __uint_as_float(raw.z << 16);
    v[i*8+5] = __uint_as_float(raw.z & 0xffff0000u);
    v[i*8+6] = __uint_as_float(raw.w << 16);
    v[i*8+7] = __uint_as_float(raw.w & 0xffff0000u);
  }
  unsigned long long alive = ~0ull;
  for (int it = 0; it < NCAND; ++it) {
    float best = -3.0e38f; int bslot = 0;
#pragma unroll
    for (int s = 0; s < 64; ++s) {
      bool ok = (alive >> s) & 1ull;
      if (ok && v[s] > best) { best = v[s]; bslot = s; }
    }
    unsigned int g = ((unsigned)(bslot >> 3)) * 512u + (unsigned)lane * 8u + (unsigned)(bslot & 7);
    float m = best; unsigned int mg = g;
#pragma unroll
    for (int off = 32; off; off >>= 1) {
      float om = __shfl_xor(m, off);
      unsigned int og = __shfl_xor(mg, off);
      if (om > m || (om == m && og < mg)) { m = om; mg = og; }
    }
    if (lane == (int)((mg >> 3) & 63u)) {
      int s = (int)(((mg >> 9) << 3) | (mg & 7u));
      alive &= ~(1ull << s);
    }
    if (lane == 0) cand[(size_t)t * NCAND + it] = (int)mg;
  }
}

// ---------------- K5: exact fp64 rescore, software-pipelined ----------------
// 512 threads = 8 waves per token; wave handles 5 candidates with 2 rotating
// row buffers (next row's loads in flight under current row's f64 FMA chain);
// all 5 cross-lane reductions batched at the end (5-way ILP on shuffles).
__global__ __launch_bounds__(512) void k5_rescore(const float* __restrict__ x,
                                                  const float* __restrict__ r,
                                                  const float* __restrict__ nw,
                                                  const float* __restrict__ Wc,
                                                  const float* __restrict__ temp,
                                                  const int* __restrict__ cand,
                                                  double* __restrict__ cval) {
  __shared__ float xs[D_DIM];
  int t = blockIdx.x;
  int tid = threadIdx.x;
  int wv = tid >> 6, lane = tid & 63;
  float rr = r[t];
  {
    float4 xv = ((const float4*)(x + (size_t)t * D_DIM))[tid];
    float4 nv = ((const float4*)nw)[tid];
    float4 o;
    o.x = xv.x * rr * nv.x; o.y = xv.y * rr * nv.y;
    o.z = xv.z * rr * nv.z; o.w = xv.w * rr * nv.w;
    ((float4*)xs)[tid] = o;
  }
  __syncthreads();
  float tclamp = fmaxf(temp[0], 0.1f);
  const int base = t * NCAND + wv * 5;
  int g0 = cand[base + 0], g1 = cand[base + 1], g2 = cand[base + 2],
      g3 = cand[base + 3], g4 = cand[base + 4];
  const float4* xs4 = (const float4*)xs;
  float4 A[8], B[8];
  double s0a = 0, s0b = 0, s1a = 0, s1b = 0, s2a = 0, s2b = 0,
         s3a = 0, s3b = 0, s4a = 0, s4b = 0;

#define LOADROW(buf, g) { \
  const float4* w4_ = (const float4*)(Wc + (size_t)(g) * D_DIM); \
  _Pragma("unroll") for (int i_ = 0; i_ < 8; ++i_) buf[i_] = w4_[i_ * 64 + lane]; }

#define COMPROW(buf, sa, sb) { \
  _Pragma("unroll") for (int i_ = 0; i_ < 8; ++i_) { \
    float4 xv_ = xs4[i_ * 64 + lane]; \
    sa += (double)xv_.x * (double)buf[i_].x + (double)xv_.z * (double)buf[i_].z; \
    sb += (double)xv_.y * (double)buf[i_].y + (double)xv_.w * (double)buf[i_].w; } }

  LOADROW(A, g0);
  LOADROW(B, g1);
  COMPROW(A, s0a, s0b);
  LOADROW(A, g2);
  COMPROW(B, s1a, s1b);
  LOADROW(B, g3);
  COMPROW(A, s2a, s2b);
  LOADROW(A, g4);
  COMPROW(B, s3a, s3b);
  COMPROW(A, s4a, s4b);
#undef LOADROW
#undef COMPROW

  double s0 = s0a + s0b, s1 = s1a + s1b, s2 = s2a + s2b,
         s3 = s3a + s3b, s4 = s4a + s4b;
#pragma unroll
  for (int off = 32; off; off >>= 1) {
    s0 += __shfl_down(s0, off);
    s1 += __shfl_down(s1, off);
    s2 += __shfl_down(s2, off);
    s3 += __shfl_down(s3, off);
    s4 += __shfl_down(s4, off);
  }
  if (lane == 0) {
    cval[base + 0] = s0 / (double)tclamp;
    cval[base + 1] = s1 / (double)tclamp;
    cval[base + 2] = s2 / (double)tclamp;
    cval[base + 3] = s3 / (double)tclamp;
    cval[base + 4] = s4 / (double)tclamp;
  }
}

// ---------------- K6: select top-32, softmax, combine -> expressed (bf16 hi/lo) ----------------
__global__ __launch_bounds__(256) void k6_express(const double* __restrict__ cval,
                                                  const int* __restrict__ cand,
                                                  const float* __restrict__ genes,
                                                  unsigned short* __restrict__ e_hi,
                                                  unsigned short* __restrict__ e_lo) {
  int t = blockIdx.x, tid = threadIdx.x;
  __shared__ double sval[NCAND];
  __shared__ int sidx[NCAND];
  __shared__ float sw[NCAND];
  if (tid < NCAND) {
    sval[tid] = cval[(size_t)t * NCAND + tid];
    sidx[tid] = cand[(size_t)t * NCAND + tid];
  }
  __syncthreads();
  if (tid < 64) {
    double v = (tid < NCAND) ? sval[tid] : -1.0e300;
    int gi = (tid < NCAND) ? sidx[tid] : 0x7fffffff;
    int rank = 0;
    for (int j = 0; j < NCAND; ++j) {
      double vj = sval[j]; int gj = sidx[j];
      if (vj > v || (vj == v && gj < gi)) rank++;
    }
    bool sel = (tid < NCAND) && (rank < KSEL);
    double vs = sel ? v : -1.0e300;
    double mx = vs;
    for (int off = 32; off; off >>= 1) { double o = __shfl_xor(mx, off); mx = fmax(mx, o); }
    double e = sel ? exp(v - mx) : 0.0;
    double ssum = e;
    for (int off = 32; off; off >>= 1) ssum += __shfl_xor(ssum, off);
    if (tid < NCAND) sw[tid] = (float)(e / ssum);
  }
  __syncthreads();
  float a0 = 0.f, a1 = 0.f, a2 = 0.f, a3 = 0.f;
#pragma unroll
  for (int k = 0; k < NCAND; k += 4) {
    a0 += sw[k]     * genes[(size_t)sidx[k]     * GD_DIM + tid];
    a1 += sw[k + 1] * genes[(size_t)sidx[k + 1] * GD_DIM + tid];
    a2 += sw[k + 2] * genes[(size_t)sidx[k + 2] * GD_DIM + tid];
    a3 += sw[k + 3] * genes[(size_t)sidx[k + 3] * GD_DIM + tid];
  }
  float acc = (a0 + a1) + (a2 + a3);
  unsigned short h = f2bf(acc);
  unsigned short l = f2bf(acc - bf2f(h));
  e_hi[(size_t)t * GD_DIM + tid] = h;
  e_lo[(size_t)t * GD_DIM + tid] = l;
}

// ---------------- K7: bf16-split MFMA down/up GEMM + tanh + xn + scale -> out ----------------
// A = expressed [M][256] (hi/lo), B = Wd/Wu [2048][256] (hi/lo). Tile 128(M) x 64(N), BK=32.
__global__ __launch_bounds__(256) void k7_mfma(const unsigned short* __restrict__ e_hi,
                                               const unsigned short* __restrict__ e_lo,
                                               const unsigned short* __restrict__ wdh,
                                               const unsigned short* __restrict__ wdl,
                                               const unsigned short* __restrict__ wuh,
                                               const unsigned short* __restrict__ wul,
                                               const float* __restrict__ x,
                                               const float* __restrict__ r,
                                               const float* __restrict__ nw,
                                               const float* __restrict__ scale_p,
                                               float* __restrict__ out) {
  __shared__ unsigned short Ah[128 * 32], Al[128 * 32];
  __shared__ unsigned short Dh[64 * 32], Dl[64 * 32], Uh[64 * 32], Ul[64 * 32];
  int tid = threadIdx.x;
  int lane = tid & 63, wv = tid >> 6;
  int bn = blockIdx.x, bm = blockIdx.y;
  int wr = wv >> 1, wc = wv & 1;   // wave tile: 64(M) x 32(N)
  const int lrow = lane >> 2;
  const int lcol = (lane & 3) * 8;

  f32x4 accD[4][2], accU[4][2];
#pragma unroll
  for (int m = 0; m < 4; ++m)
#pragma unroll
    for (int n = 0; n < 2; ++n) {
      accD[m][n] = (f32x4){0.f, 0.f, 0.f, 0.f};
      accU[m][n] = (f32x4){0.f, 0.f, 0.f, 0.f};
    }

  for (int kt = 0; kt < GD_DIM; kt += 32) {
    __syncthreads();
#pragma unroll
    for (int c = 0; c < 8; ++c) {
      int cid = wv * 8 + c;
      if (cid < 8) {
        async_copy16(e_hi + (size_t)(bm * 128 + cid * 16 + lrow) * GD_DIM + kt + lcol,
                     &Ah[cid * 512]);
      } else if (cid < 16) {
        int cc = cid - 8;
        async_copy16(e_lo + (size_t)(bm * 128 + cc * 16 + lrow) * GD_DIM + kt + lcol,
                     &Al[cc * 512]);
      } else if (cid < 20) {
        int cc = cid - 16;
        async_copy16(wdh + (size_t)(bn * 64 + cc * 16 + lrow) * GD_DIM + kt + lcol,
                     &Dh[cc * 512]);
      } else if (cid < 24) {
        int cc = cid - 20;
        async_copy16(wdl + (size_t)(bn * 64 + cc * 16 + lrow) * GD_DIM + kt + lcol,
                     &Dl[cc * 512]);
      } else if (cid < 28) {
        int cc = cid - 24;
        async_copy16(wuh + (size_t)(bn * 64 + cc * 16 + lrow) * GD_DIM + kt + lcol,
                     &Uh[cc * 512]);
      } else {
        int cc = cid - 28;
        async_copy16(wul + (size_t)(bn * 64 + cc * 16 + lrow) * GD_DIM + kt + lcol,
                     &Ul[cc * 512]);
      }
    }
    __syncthreads();
    bf16x8 fah[4], fal[4], fdh[2], fdl[2], fuh[2], ful[2];
#pragma unroll
    for (int m = 0; m < 4; ++m) {
      int off = (wr * 64 + m * 16 + (lane & 15)) * 32 + (lane >> 4) * 8;
      fah[m] = *(const bf16x8*)&Ah[off];
      fal[m] = *(const bf16x8*)&Al[off];
    }
#pragma unroll
    for (int n = 0; n < 2; ++n) {
      int off = (wc * 32 + n * 16 + (lane & 15)) * 32 + (lane >> 4) * 8;
      fdh[n] = *(const bf16x8*)&Dh[off];
      fdl[n] = *(const bf16x8*)&Dl[off];
      fuh[n] = *(const bf16x8*)&Uh[off];
      ful[n] = *(const bf16x8*)&Ul[off];
    }
#pragma unroll
    for (int m = 0; m < 4; ++m)
#pragma unroll
      for (int n = 0; n < 2; ++n) {
        accD[m][n] = __builtin_amdgcn_mfma_f32_16x16x32_bf16(fah[m], fdh[n], accD[m][n], 0, 0, 0);
        accD[m][n] = __builtin_amdgcn_mfma_f32_16x16x32_bf16(fah[m], fdl[n], accD[m][n], 0, 0, 0);
        accD[m][n] = __builtin_amdgcn_mfma_f32_16x16x32_bf16(fal[m], fdh[n], accD[m][n], 0, 0, 0);
        accU[m][n] = __builtin_amdgcn_mfma_f32_16x16x32_bf16(fah[m], fuh[n], accU[m][n], 0, 0, 0);
        accU[m][n] = __builtin_amdgcn_mfma_f32_16x16x32_bf16(fah[m], ful[n], accU[m][n], 0, 0, 0);
        accU[m][n] = __builtin_amdgcn_mfma_f32_16x16x32_bf16(fal[m], fuh[n], accU[m][n], 0, 0, 0);
      }
  }
  float sc = scale_p[0];
#pragma unroll
  for (int m = 0; m < 4; ++m)
#pragma unroll
    for (int j = 0; j < 4; ++j) {
      int token = bm * 128 + wr * 64 + m * 16 + (lane >> 4) * 4 + j;
      float rr = r[token];
#pragma unroll
      for (int n = 0; n < 2; ++n) {
        int d = bn * 64 + wc * 32 + n * 16 + (lane & 15);
        float xn = x[(size_t)token * D_DIM + d] * rr * nw[d];
        out[(size_t)token * D_DIM + d] = tanhf(accD[m][n][j]) * xn * accU[m][n][j] * sc;
      }
    }
}

extern "C" void kernel_launch(void* const* d_in, const int* in_sizes, int n_in,
                              void* d_out, int out_size, void* d_ws, size_t ws_size,
                              hipStream_t stream) {
  const float* x       = (const float*)d_in[0];
  const float* Wc      = (const float*)d_in[1];
  const float* temp    = (const float*)d_in[2];
  const float* genes   = (const float*)d_in[3];
  const float* Wd      = (const float*)d_in[4];
  const float* Wu      = (const float*)d_in[5];
  const float* nw      = (const float*)d_in[6];
  const float* scale_p = (const float*)d_in[7];

  char* ws = (char*)d_ws;
  float* r_buf          = (float*)ws;                                   // 32 KB (64 KB reserved)
  unsigned short* xn_bf = (unsigned short*)(ws + 65536);                // 32 MB (free after k3)
  unsigned short* wc_bf = (unsigned short*)(ws + 65536 + (size_t)M_TOK * D_DIM * 2);   // 16 MB
  char* p = ws + 65536 + (size_t)M_TOK * D_DIM * 2 + (size_t)G_GENES * D_DIM * 2;
  int* cand    = (int*)p;                       p += (size_t)M_TOK * NCAND * 4;
  double* cval = (double*)p;                    p += (size_t)M_TOK * NCAND * 8;
  unsigned short* e_hi = (unsigned short*)p;    p += (size_t)M_TOK * GD_DIM * 2;
  unsigned short* e_lo = (unsigned short*)p;

  // Wd/Wu bf16 hi/lo splits live in the xn_bf region (dead after k3): 4 x 1 MB
  unsigned short* wdh = (unsigned short*)(ws + 65536);
  unsigned short* wdl = wdh + (size_t)D_DIM * GD_DIM;
  unsigned short* wuh = wdl + (size_t)D_DIM * GD_DIM;
  unsigned short* wul = wuh + (size_t)D_DIM * GD_DIM;

  unsigned short* logits_bf = (unsigned short*)d_out;  // 33.5M bf16 == 64 MB == d_out

  k1_rmsnorm<<<dim3(M_TOK), dim3(256), 0, stream>>>(x, nw, r_buf, xn_bf);
  k2_cvt<<<dim3((G_GENES * D_DIM) / (256 * 8)), dim3(256), 0, stream>>>(Wc, wc_bf);
  k3_gemm_logits<<<dim3(G_GENES / 128, M_TOK / 128), dim3(256), 0, stream>>>(xn_bf, wc_bf, logits_bf);
  k4_topk<<<dim3(M_TOK / 4), dim3(256), 0, stream>>>(logits_bf, cand);
  k2b_split<<<dim3((D_DIM * GD_DIM) / (256 * 4), 2), dim3(256), 0, stream>>>(Wd, Wu, wdh, wdl, wuh, wul);
  k5_rescore<<<dim3(M_TOK), dim3(512), 0, stream>>>(x, r_buf, nw, Wc, temp, cand, cval);
  k6_express<<<dim3(M_TOK), dim3(256), 0, stream>>>(cval, cand, genes, e_hi, e_lo);
  k7_mfma<<<dim3(D_DIM / 64, M_TOK / 128), dim3(256), 0, stream>>>(e_hi, e_lo, wdh, wdl, wuh, wul,
                                                                   x, r_buf, nw, scale_p, (float*)d_out);
}